// Round 10
// baseline (194.201 us; speedup 1.0000x reference)
//
#include <hip/hip_runtime.h>

// Problem constants (reference: B=4096, C=1000, T_THR=2, T_KD=20, ALPHA=0.8)
constexpr int   B        = 4096;
constexpr int   C        = 1000;
constexpr float ALPHA    = 0.8f;
constexpr float INV_TKD  = 0.05f;    // 1/20
constexpr float TKD2     = 400.0f;   // 20*20
constexpr float INV_TTHR = 0.5f;     // 1/2
constexpr float SENT     = -1e30f;   // finite sentinel (exp -> 0, fmax-neutral)

// ---------------------------------------------------------------------------
// Kernel 1: two waves per row (8 elems/lane), 128-thr block, grid = B.
// Round-9 post-mortem: spill fixed (WRITE 385KB) but row stuck at 58us with
// VGPR=44 / VALUBusy 29% / occupancy 38% -> MLP-starved: depth-1 prefetch
// leaves each wave stalling ~650cy per teacher, 9x serially. The 9 row
// addresses are independent, so this version ISSUES ALL LOADS UPFRONT:
//   * 18 dwordx4 (S + 8 teachers) in flight per wave; compiler inserts
//     counted s_waitcnt vmcnt(N) before each teacher's partials -> one
//     latency absorption per wave instead of nine
//   * teacher loop remains PURE VALU (no shuffle/LDS/barrier) so nothing
//     drains the vmcnt queue mid-stream (round-7 lesson)
//   * deferred reductions: ONE batched 39-way butterfly + ONE barrier
//     cross-wave combine + wave-uniform tail (byte-identical to round-9's
//     absmax-0.0 kernel)
//   * buf[8][8] fully static-indexed after unroll (rule: no runtime idx)
// ---------------------------------------------------------------------------
__global__ __launch_bounds__(128, 4) void row_kernel(
    const float* __restrict__ T0, const float* __restrict__ T1,
    const float* __restrict__ T2, const float* __restrict__ T3,
    const float* __restrict__ T4, const float* __restrict__ T5,
    const float* __restrict__ T6, const float* __restrict__ T7,
    const float* __restrict__ S,  const int* __restrict__ TGT,
    float* __restrict__ ws_ce, float* __restrict__ ws_g, float* __restrict__ ws_m)
{
    __shared__ float4 xch[2][10];       // per-wave reduced state (320 B)

    const int tid  = threadIdx.x;
    const int lane = tid & 63;
    const int h    = tid >> 6;          // half-row index (wave 0/1)
    const int row  = blockIdx.x;
    const size_t base = (size_t)row * C;

    const int  tgt   = TGT[row];                    // wave-uniform
    const int  ftgt  = tgt >> 2;                    // float4 index of target
    const bool own   = (h == (ftgt >> 7));          // which half owns it
    const int  uidx  = (((ftgt >> 6) & 1) << 2) | (tgt & 3);  // reg slot in v[8]
    const int  slane = ftgt & 63;                   // lane that owns it
    const bool owner = own && (lane == slane);      // unique owner thread

    // branchless 2x float4 half-row load; h=1,k=1 covers float4s [192,250),
    // lanes >=58 there get the sentinel (address clamped to float4 #0)
    auto load_half = [&](const float* __restrict__ p, float (&v)[8]) {
        const float4* p4 = (const float4*)(p + base);
#pragma unroll
        for (int k = 0; k < 2; ++k) {
            const int  idx = lane + 128 * h + 64 * k;   // 250 float4s per row
            const bool ok  = (h == 0) || (k == 0) || (lane < 58);
            float4 f = p4[ok ? idx : 0];
            v[4*k+0] = ok ? f.x : SENT;
            v[4*k+1] = ok ? f.y : SENT;
            v[4*k+2] = ok ? f.z : SENT;
            v[4*k+3] = ok ? f.w : SENT;
        }
    };

    // ---------------- issue ALL loads upfront (18 dwordx4 in flight) -------
    float sv[8];
    load_half(S, sv);
    float buf[8][8];
    const float* ptrs[8] = {T0, T1, T2, T3, T4, T5, T6, T7};
#pragma unroll
    for (int t = 0; t < 8; ++t)
        load_half(ptrs[t], buf[t]);     // independent addresses: all in flight

    // ---------------- student per-lane partials (sv arrives first) ---------
    // unshifted exps; safe for N(0,1) logits
    float z1 = 0.0f, zT = 0.0f, sc = SENT;
#pragma unroll
    for (int i = 0; i < 8; ++i) {
        z1 += __expf(sv[i]);
        zT += __expf(sv[i] * INV_TKD);
        sc = (owner && i == uidx) ? sv[i] : sc;     // only owner contributes
    }

    // deferred per-branch state: index b is compile-time after unrolling
    float mxA[9], ZA[9], SdA[9], tvA[9];

    auto partials = [&](const float (&v)[8], const int b) {
        float cand = SENT, m_all = SENT, m_ex = SENT, Z = 0.0f, Sd = 0.0f;
#pragma unroll
        for (int i = 0; i < 8; ++i) {
            const float x = v[i];
            cand  = (i == uidx) ? x : cand;
            m_all = fmaxf(m_all, x);
            m_ex  = fmaxf(m_ex, (i == uidx) ? SENT : x);
            const float e = __expf(x * INV_TKD);    // exp(-5e28)=0 for sentinel
            Z += e;
            Sd = fmaf(e, sv[i], Sd);                // e==0 kills sentinel sv
        }
        mxA[b] = owner ? m_ex : m_all;              // owner excludes target
        ZA[b]  = Z;
        SdA[b] = Sd;
        tvA[b] = owner ? cand : SENT;               // tv via max-reduction
    };

    // ---------------- consume teachers in arrival order (pure VALU) --------
    float acc[8];
#pragma unroll
    for (int i = 0; i < 8; ++i) acc[i] = 0.0f;      // mimic accumulator
#pragma unroll
    for (int t = 0; t < 8; ++t) {
        const float (&cv)[8] = buf[t];              // counted vmcnt wait here
#pragma unroll
        for (int i = 0; i < 8; ++i) acc[i] += cv[i];
        partials(cv, t);                            // no barrier, no shuffle
    }

    // mimic = mean of 8 teachers (9th branch; excluded from max_preds)
#pragma unroll
    for (int i = 0; i < 8; ++i) acc[i] *= 0.125f;
    partials(acc, 8);

    // ---------------- ONE batched butterfly: 39 independent reductions -----
#pragma unroll
    for (int m = 1; m < 64; m <<= 1) {
#pragma unroll
        for (int b = 0; b < 9; ++b) {
            mxA[b]  = fmaxf(mxA[b], __shfl_xor(mxA[b], m, 64));
            ZA[b]  += __shfl_xor(ZA[b], m, 64);
            SdA[b] += __shfl_xor(SdA[b], m, 64);
            tvA[b]  = fmaxf(tvA[b], __shfl_xor(tvA[b], m, 64));
        }
        z1 += __shfl_xor(z1, m, 64);
        zT += __shfl_xor(zT, m, 64);
        sc  = fmaxf(sc, __shfl_xor(sc, m, 64));
    }

    // ---------------- ONE barrier: cross-wave combine -----------------------
    if (lane == 0) {
#pragma unroll
        for (int b = 0; b < 9; ++b)
            xch[h][b] = make_float4(mxA[b], ZA[b], SdA[b], tvA[b]);
        xch[h][9] = make_float4(z1, zT, sc, 0.0f);
    }
    __syncthreads();
#pragma unroll
    for (int b = 0; b < 9; ++b) {
        const float4 o = xch[h ^ 1][b];             // partner wave's values
        mxA[b]  = fmaxf(mxA[b], o.x);               // commutative combine:
        ZA[b]  += o.y;                              // both waves identical
        SdA[b] += o.z;
        tvA[b]  = fmaxf(tvA[b], o.w);
    }
    {
        const float4 o = xch[h ^ 1][9];
        z1 += o.x; zT += o.y; sc = fmaxf(sc, o.z);
    }

    // ---------------- wave-uniform scalar tail ------------------------------
    const float logZT = __logf(zT);
    const float ce    = __logf(z1) - sc;            // student cross-entropy

    float s1 = 0.0f, s2 = 0.0f, rowmax8 = SENT;
#pragma unroll
    for (int b = 0; b < 9; ++b) {
        const float mx = mxA[b], Z = ZA[b], Sd = SdA[b], tv = tvA[b];
        const float margin = fmaxf(tv - mx, 0.0f);  // exact: ties -> 0
        const float kd = TKD2 * (logZT - INV_TKD * __fdividef(Sd, Z));
        const float u  = tv * (kd - ce);
        const float w8 = __expf(margin * INV_TTHR); // margin in [0,~10]
        s1 += w8;
        s2  = fmaf(w8, u, s2);
        if (b < 8) rowmax8 = fmaxf(rowmax8, fmaxf(mx, tv));
    }

    if (tid == 0) {
        ws_ce[row] = ce;
        ws_g[row]  = s2 / s1;
        ws_m[row]  = rowmax8;
    }
}

// ---------------------------------------------------------------------------
// Kernel 2: single block. max_preds over rows, then f64-accumulated mean of
// CE_b + (ALPHA/max_preds) * G_b. Verified in rounds 3/7/9.
// ---------------------------------------------------------------------------
__global__ __launch_bounds__(256) void fin_kernel(
    const float* __restrict__ ce, const float* __restrict__ g,
    const float* __restrict__ m, float* __restrict__ out)
{
    __shared__ float  smax[4];
    __shared__ double ssum[4];
    const int tid  = threadIdx.x;
    const int lane = tid & 63;
    const int wid  = tid >> 6;

    float mx = SENT;
    for (int i = tid; i < B; i += 256) mx = fmaxf(mx, m[i]);
#pragma unroll
    for (int k = 1; k < 64; k <<= 1) mx = fmaxf(mx, __shfl_xor(mx, k, 64));
    if (lane == 0) smax[wid] = mx;
    __syncthreads();
    const float scale =
        ALPHA / fmaxf(fmaxf(smax[0], smax[1]), fmaxf(smax[2], smax[3]));

    double acc = 0.0;
    for (int i = tid; i < B; i += 256) acc += (double)(ce[i] + g[i] * scale);
#pragma unroll
    for (int k = 1; k < 64; k <<= 1) acc += __shfl_xor(acc, k, 64);
    if (lane == 0) ssum[wid] = acc;
    __syncthreads();
    if (tid == 0)
        out[0] = (float)((ssum[0] + ssum[1] + ssum[2] + ssum[3]) *
                         (1.0 / (double)B));
}

extern "C" void kernel_launch(void* const* d_in, const int* in_sizes, int n_in,
                              void* d_out, int out_size, void* d_ws, size_t ws_size,
                              hipStream_t stream)
{
    const float* T0 = (const float*)d_in[0];
    const float* T1 = (const float*)d_in[1];
    const float* T2 = (const float*)d_in[2];
    const float* T3 = (const float*)d_in[3];
    const float* T4 = (const float*)d_in[4];
    const float* T5 = (const float*)d_in[5];
    const float* T6 = (const float*)d_in[6];
    const float* T7 = (const float*)d_in[7];
    const float* S  = (const float*)d_in[8];
    const int*   TG = (const int*)d_in[9];

    float* ws = (float*)d_ws;
    float* ws_ce = ws;
    float* ws_g  = ws + B;
    float* ws_m  = ws + 2 * B;

    row_kernel<<<B, 128, 0, stream>>>(T0, T1, T2, T3, T4, T5, T6, T7,
                                      S, TG, ws_ce, ws_g, ws_m);
    fin_kernel<<<1, 256, 0, stream>>>(ws_ce, ws_g, ws_m, (float*)d_out);
}

// Round 13
// 190.445 us; speedup vs baseline: 1.0197x; 1.0197x over previous
//
#include <hip/hip_runtime.h>

// Problem constants (reference: B=4096, C=1000, T_THR=2, T_KD=20, ALPHA=0.8)
constexpr int   B        = 4096;
constexpr int   C        = 1000;
constexpr float ALPHA    = 0.8f;
constexpr float INV_TKD  = 0.05f;    // 1/20
constexpr float TKD2     = 400.0f;   // 20*20
constexpr float INV_TTHR = 0.5f;     // 1/2
constexpr float SENT     = -1e30f;   // finite sentinel (exp -> 0, fmax-neutral)

// ---------------------------------------------------------------------------
// Kernel 1: two waves per row (8 elems/lane), 128-thr block, grid = B.
// Round-10 post-mortem: "issue all loads upfront" was DEFEATED by the machine
// scheduler (VGPR stayed 44 -> loads re-sunk to just-in-time; row time
// unchanged at ~60us = 9 serial ~800cy latency absorptions per wave).
// This version pins the schedule:
//   * 18 dwordx4 (S + 8 teachers) issued, then __builtin_amdgcn_sched_barrier(0)
//     -- no instruction may cross: loads stay issued BEFORE all compute, so
//     all 9 row-loads are in flight concurrently; compiler still emits its
//     own counted s_waitcnt vmcnt(N) at each consumer -> ONE latency
//     absorption per wave instead of nine
//   * consumption in issue order; teacher loop stays PURE VALU (no
//     shuffle/LDS/barrier -> nothing drains vmcnt mid-stream, r7 lesson)
//   * deferred reductions: ONE batched 39-way butterfly + ONE barrier
//     cross-wave combine + wave-uniform tail (byte-identical math to the
//     absmax-0.0 kernels of rounds 9/10)
//   * expected VGPR ~95-110 (must hold 72 in-flight floats); cap 128 via
//     __launch_bounds__(128,4); occupancy cap 4 waves/SIMD >= measured ~3
// ---------------------------------------------------------------------------
__global__ __launch_bounds__(128, 4) void row_kernel(
    const float* __restrict__ T0, const float* __restrict__ T1,
    const float* __restrict__ T2, const float* __restrict__ T3,
    const float* __restrict__ T4, const float* __restrict__ T5,
    const float* __restrict__ T6, const float* __restrict__ T7,
    const float* __restrict__ S,  const int* __restrict__ TGT,
    float* __restrict__ ws_ce, float* __restrict__ ws_g, float* __restrict__ ws_m)
{
    __shared__ float4 xch[2][10];       // per-wave reduced state (320 B)

    const int tid  = threadIdx.x;
    const int lane = tid & 63;
    const int h    = tid >> 6;          // half-row index (wave 0/1)
    const int row  = blockIdx.x;
    const size_t base = (size_t)row * C;

    const int  tgt   = TGT[row];                    // wave-uniform
    const int  ftgt  = tgt >> 2;                    // float4 index of target
    const bool own   = (h == (ftgt >> 7));          // which half owns it
    const int  uidx  = (((ftgt >> 6) & 1) << 2) | (tgt & 3);  // reg slot in v[8]
    const int  slane = ftgt & 63;                   // lane that owns it
    const bool owner = own && (lane == slane);      // unique owner thread

    // branchless 2x float4 half-row load; h=1,k=1 covers float4s [192,250),
    // lanes >=58 there get the sentinel (address clamped to float4 #0)
    auto load_half = [&](const float* __restrict__ p, float (&v)[8]) {
        const float4* p4 = (const float4*)(p + base);
#pragma unroll
        for (int k = 0; k < 2; ++k) {
            const int  idx = lane + 128 * h + 64 * k;   // 250 float4s per row
            const bool ok  = (h == 0) || (k == 0) || (lane < 58);
            float4 f = p4[ok ? idx : 0];
            v[4*k+0] = ok ? f.x : SENT;
            v[4*k+1] = ok ? f.y : SENT;
            v[4*k+2] = ok ? f.z : SENT;
            v[4*k+3] = ok ? f.w : SENT;
        }
    };

    // ---------------- issue ALL loads, then PIN them above all compute -----
    float sv[8];
    load_half(S, sv);                   // needed first -> issued first
    float buf[8][8];
    const float* ptrs[8] = {T0, T1, T2, T3, T4, T5, T6, T7};
#pragma unroll
    for (int t = 0; t < 8; ++t)
        load_half(ptrs[t], buf[t]);     // independent addresses: all in flight

    __builtin_amdgcn_sched_barrier(0);  // loads may NOT sink below this point

    // ---------------- student per-lane partials (sv arrives first) ---------
    // unshifted exps; safe for N(0,1) logits
    float z1 = 0.0f, zT = 0.0f, sc = SENT;
#pragma unroll
    for (int i = 0; i < 8; ++i) {
        z1 += __expf(sv[i]);
        zT += __expf(sv[i] * INV_TKD);
        sc = (owner && i == uidx) ? sv[i] : sc;     // only owner contributes
    }

    // deferred per-branch state: index b is compile-time after unrolling
    float mxA[9], ZA[9], SdA[9], tvA[9];

    auto partials = [&](const float (&v)[8], const int b) {
        float cand = SENT, m_all = SENT, m_ex = SENT, Z = 0.0f, Sd = 0.0f;
#pragma unroll
        for (int i = 0; i < 8; ++i) {
            const float x = v[i];
            cand  = (i == uidx) ? x : cand;
            m_all = fmaxf(m_all, x);
            m_ex  = fmaxf(m_ex, (i == uidx) ? SENT : x);
            const float e = __expf(x * INV_TKD);    // exp(-5e28)=0 for sentinel
            Z += e;
            Sd = fmaf(e, sv[i], Sd);                // e==0 kills sentinel sv
        }
        mxA[b] = owner ? m_ex : m_all;              // owner excludes target
        ZA[b]  = Z;
        SdA[b] = Sd;
        tvA[b] = owner ? cand : SENT;               // tv via max-reduction
    };

    // ---------------- consume teachers in issue order (pure VALU) ----------
    float acc[8];
#pragma unroll
    for (int i = 0; i < 8; ++i) acc[i] = 0.0f;      // mimic accumulator
#pragma unroll
    for (int t = 0; t < 8; ++t) {
        const float (&cv)[8] = buf[t];              // counted vmcnt wait here
#pragma unroll
        for (int i = 0; i < 8; ++i) acc[i] += cv[i];
        partials(cv, t);                            // no barrier, no shuffle
    }

    // mimic = mean of 8 teachers (9th branch; excluded from max_preds)
#pragma unroll
    for (int i = 0; i < 8; ++i) acc[i] *= 0.125f;
    partials(acc, 8);

    // ---------------- ONE batched butterfly: 39 independent reductions -----
#pragma unroll
    for (int m = 1; m < 64; m <<= 1) {
#pragma unroll
        for (int b = 0; b < 9; ++b) {
            mxA[b]  = fmaxf(mxA[b], __shfl_xor(mxA[b], m, 64));
            ZA[b]  += __shfl_xor(ZA[b], m, 64);
            SdA[b] += __shfl_xor(SdA[b], m, 64);
            tvA[b]  = fmaxf(tvA[b], __shfl_xor(tvA[b], m, 64));
        }
        z1 += __shfl_xor(z1, m, 64);
        zT += __shfl_xor(zT, m, 64);
        sc  = fmaxf(sc, __shfl_xor(sc, m, 64));
    }

    // ---------------- ONE barrier: cross-wave combine -----------------------
    if (lane == 0) {
#pragma unroll
        for (int b = 0; b < 9; ++b)
            xch[h][b] = make_float4(mxA[b], ZA[b], SdA[b], tvA[b]);
        xch[h][9] = make_float4(z1, zT, sc, 0.0f);
    }
    __syncthreads();
#pragma unroll
    for (int b = 0; b < 9; ++b) {
        const float4 o = xch[h ^ 1][b];             // partner wave's values
        mxA[b]  = fmaxf(mxA[b], o.x);               // commutative combine:
        ZA[b]  += o.y;                              // both waves identical
        SdA[b] += o.z;
        tvA[b]  = fmaxf(tvA[b], o.w);
    }
    {
        const float4 o = xch[h ^ 1][9];
        z1 += o.x; zT += o.y; sc = fmaxf(sc, o.z);
    }

    // ---------------- wave-uniform scalar tail ------------------------------
    const float logZT = __logf(zT);
    const float ce    = __logf(z1) - sc;            // student cross-entropy

    float s1 = 0.0f, s2 = 0.0f, rowmax8 = SENT;
#pragma unroll
    for (int b = 0; b < 9; ++b) {
        const float mx = mxA[b], Z = ZA[b], Sd = SdA[b], tv = tvA[b];
        const float margin = fmaxf(tv - mx, 0.0f);  // exact: ties -> 0
        const float kd = TKD2 * (logZT - INV_TKD * __fdividef(Sd, Z));
        const float u  = tv * (kd - ce);
        const float w8 = __expf(margin * INV_TTHR); // margin in [0,~10]
        s1 += w8;
        s2  = fmaf(w8, u, s2);
        if (b < 8) rowmax8 = fmaxf(rowmax8, fmaxf(mx, tv));
    }

    if (tid == 0) {
        ws_ce[row] = ce;
        ws_g[row]  = s2 / s1;
        ws_m[row]  = rowmax8;
    }
}

// ---------------------------------------------------------------------------
// Kernel 2: single block. max_preds over rows, then f64-accumulated mean of
// CE_b + (ALPHA/max_preds) * G_b. Verified in rounds 3/7/9/10.
// ---------------------------------------------------------------------------
__global__ __launch_bounds__(256) void fin_kernel(
    const float* __restrict__ ce, const float* __restrict__ g,
    const float* __restrict__ m, float* __restrict__ out)
{
    __shared__ float  smax[4];
    __shared__ double ssum[4];
    const int tid  = threadIdx.x;
    const int lane = tid & 63;
    const int wid  = tid >> 6;

    float mx = SENT;
    for (int i = tid; i < B; i += 256) mx = fmaxf(mx, m[i]);
#pragma unroll
    for (int k = 1; k < 64; k <<= 1) mx = fmaxf(mx, __shfl_xor(mx, k, 64));
    if (lane == 0) smax[wid] = mx;
    __syncthreads();
    const float scale =
        ALPHA / fmaxf(fmaxf(smax[0], smax[1]), fmaxf(smax[2], smax[3]));

    double acc = 0.0;
    for (int i = tid; i < B; i += 256) acc += (double)(ce[i] + g[i] * scale);
#pragma unroll
    for (int k = 1; k < 64; k <<= 1) acc += __shfl_xor(acc, k, 64);
    if (lane == 0) ssum[wid] = acc;
    __syncthreads();
    if (tid == 0)
        out[0] = (float)((ssum[0] + ssum[1] + ssum[2] + ssum[3]) *
                         (1.0 / (double)B));
}

extern "C" void kernel_launch(void* const* d_in, const int* in_sizes, int n_in,
                              void* d_out, int out_size, void* d_ws, size_t ws_size,
                              hipStream_t stream)
{
    const float* T0 = (const float*)d_in[0];
    const float* T1 = (const float*)d_in[1];
    const float* T2 = (const float*)d_in[2];
    const float* T3 = (const float*)d_in[3];
    const float* T4 = (const float*)d_in[4];
    const float* T5 = (const float*)d_in[5];
    const float* T6 = (const float*)d_in[6];
    const float* T7 = (const float*)d_in[7];
    const float* S  = (const float*)d_in[8];
    const int*   TG = (const int*)d_in[9];

    float* ws = (float*)d_ws;
    float* ws_ce = ws;
    float* ws_g  = ws + B;
    float* ws_m  = ws + 2 * B;

    row_kernel<<<B, 128, 0, stream>>>(T0, T1, T2, T3, T4, T5, T6, T7,
                                      S, TG, ws_ce, ws_g, ws_m);
    fin_kernel<<<1, 256, 0, stream>>>(ws_ce, ws_g, ws_m, (float*)d_out);
}

// Round 15
// 188.678 us; speedup vs baseline: 1.0293x; 1.0094x over previous
//
#include <hip/hip_runtime.h>

// Problem constants (reference: B=4096, C=1000, T_THR=2, T_KD=20, ALPHA=0.8)
constexpr int   B        = 4096;
constexpr int   C        = 1000;
constexpr float ALPHA    = 0.8f;
constexpr float INV_TKD  = 0.05f;    // 1/20
constexpr float TKD2     = 400.0f;   // 20*20
constexpr float INV_TTHR = 0.5f;     // 1/2
constexpr float SENT     = -1e30f;   // finite sentinel (exp -> 0, fmax-neutral)

typedef float f32x4 __attribute__((ext_vector_type(4)));

// ---------------------------------------------------------------------------
// Kernel 1: two waves per row (8 elems/lane), 128-thr block, grid = B.
// r10: source-order upfront loads -> scheduler re-sank them (VGPR 44).
// r13: sched_barrier(0) pin -> only partially held (VGPR 64 < the 72 floats
// required; row time unchanged at ~58us = serial latency per teacher).
// This version makes the 18-deep load pipeline STRUCTURAL:
//   * 18x asm volatile global_load_dwordx4 (S + 8 teachers), program-order
//     pinned (volatile asm cannot reorder); "=v"(f32x4) outputs force RA to
//     keep all 72 dest VGPRs live -> the pipeline cannot be collapsed
//     without a visible spill (WRITE_SIZE tripwire)
//   * explicit counted waits: s_waitcnt vmcnt(16/14/../0) before each
//     consume batch + sched_barrier(0) after each (rule #18: hipcc hoists
//     register-only consumers past asm waitcnt otherwise). Counts are safe
//     vs compiler-inserted VMEM: extra ops can only over-wait (m135 FIFO
//     vmcnt semantics); TGT is uniform -> SMEM/lgkmcnt, not vmcnt
//   * OOB tail handled by clamped address at issue + select-to-SENT at
//     consume (branchless, no extra HBM traffic)
//   * downstream byte-identical to r9/r10/r13 absmax-0.0 kernels: pure-VALU
//     partials, ONE batched 39-way butterfly, ONE barrier cross-wave
//     combine, wave-uniform tail
// ---------------------------------------------------------------------------
__global__ __launch_bounds__(128, 4) void row_kernel(
    const float* __restrict__ T0, const float* __restrict__ T1,
    const float* __restrict__ T2, const float* __restrict__ T3,
    const float* __restrict__ T4, const float* __restrict__ T5,
    const float* __restrict__ T6, const float* __restrict__ T7,
    const float* __restrict__ S,  const int* __restrict__ TGT,
    float* __restrict__ ws_ce, float* __restrict__ ws_g, float* __restrict__ ws_m)
{
    __shared__ float4 xch[2][10];       // per-wave reduced state (320 B)

    const int tid  = threadIdx.x;
    const int lane = tid & 63;
    const int h    = tid >> 6;          // half-row index (wave 0/1)
    const int row  = blockIdx.x;
    const size_t base = (size_t)row * C;

    const int  tgt   = TGT[row];                    // wave-uniform (SMEM)
    const int  ftgt  = tgt >> 2;                    // float4 index of target
    const bool own   = (h == (ftgt >> 7));          // which half owns it
    const int  uidx  = (((ftgt >> 6) & 1) << 2) | (tgt & 3);  // reg slot in v[8]
    const int  slane = ftgt & 63;                   // lane that owns it
    const bool owner = own && (lane == slane);      // unique owner thread

    // per-lane float4 indices; k=1 on the h=1 half covers float4s [192,250),
    // lanes >=58 there are OOB -> clamp address to float4 #0, SENT at consume
    const int  idx0 = lane + 128 * h;               // always valid (<250)
    const bool ok1  = (h == 0) || (lane < 58);
    const int  idx1 = ok1 ? (idx0 + 64) : 0;

    // ------------- issue ALL 18 loads (program-order pinned by asm) --------
    f32x4 r[9][2];                                  // 72 VGPRs, all live
    {
        const float* ps[9] = {S, T0, T1, T2, T3, T4, T5, T6, T7};
#pragma unroll
        for (int j = 0; j < 9; ++j) {               // j compile-time (unroll)
            const f32x4* a0 = (const f32x4*)(ps[j] + base) + idx0;
            const f32x4* a1 = (const f32x4*)(ps[j] + base) + idx1;
            asm volatile("global_load_dwordx4 %0, %1, off"
                         : "=v"(r[j][0]) : "v"(a0));
            asm volatile("global_load_dwordx4 %0, %1, off"
                         : "=v"(r[j][1]) : "v"(a1));
        }
    }

    // raw float4 pair -> 8 floats with OOB select
    auto sel = [&](const f32x4 (&d)[2], float (&v)[8]) {
#pragma unroll
        for (int i = 0; i < 4; ++i) {
            v[i]     = d[0][i];
            v[4 + i] = ok1 ? d[1][i] : SENT;
        }
    };

    // ------------- student consume: loads 1-2 done at vmcnt(16) ------------
    asm volatile("s_waitcnt vmcnt(16)");
    __builtin_amdgcn_sched_barrier(0);
    float sv[8];
    sel(r[0], sv);
    // unshifted exps; safe for N(0,1) logits
    float z1 = 0.0f, zT = 0.0f, sc = SENT;
#pragma unroll
    for (int i = 0; i < 8; ++i) {
        z1 += __expf(sv[i]);
        zT += __expf(sv[i] * INV_TKD);
        sc = (owner && i == uidx) ? sv[i] : sc;     // only owner contributes
    }

    // deferred per-branch state: index b is compile-time after unrolling
    float mxA[9], ZA[9], SdA[9], tvA[9];

    auto partials = [&](const float (&v)[8], const int b) {
        float cand = SENT, m_all = SENT, m_ex = SENT, Z = 0.0f, Sd = 0.0f;
#pragma unroll
        for (int i = 0; i < 8; ++i) {
            const float x = v[i];
            cand  = (i == uidx) ? x : cand;
            m_all = fmaxf(m_all, x);
            m_ex  = fmaxf(m_ex, (i == uidx) ? SENT : x);
            const float e = __expf(x * INV_TKD);    // exp(-5e28)=0 for sentinel
            Z += e;
            Sd = fmaf(e, sv[i], Sd);                // e==0 kills sentinel sv
        }
        mxA[b] = owner ? m_ex : m_all;              // owner excludes target
        ZA[b]  = Z;
        SdA[b] = Sd;
        tvA[b] = owner ? cand : SENT;               // tv via max-reduction
    };

    float acc[8];
#pragma unroll
    for (int i = 0; i < 8; ++i) acc[i] = 0.0f;      // mimic accumulator

    // ------------- teacher consumes: counted waits, oldest-first -----------
#define CONSUME(T_, N_)                                          \
    asm volatile("s_waitcnt vmcnt(" #N_ ")");                    \
    __builtin_amdgcn_sched_barrier(0);                           \
    {                                                            \
        float v[8];                                              \
        sel(r[(T_) + 1], v);                                     \
        _Pragma("unroll")                                        \
        for (int i = 0; i < 8; ++i) acc[i] += v[i];              \
        partials(v, T_);                                         \
    }

    CONSUME(0, 14) CONSUME(1, 12) CONSUME(2, 10) CONSUME(3, 8)
    CONSUME(4, 6)  CONSUME(5, 4)  CONSUME(6, 2)  CONSUME(7, 0)
#undef CONSUME

    // mimic = mean of 8 teachers (9th branch; excluded from max_preds)
#pragma unroll
    for (int i = 0; i < 8; ++i) acc[i] *= 0.125f;
    partials(acc, 8);

    // ------------- ONE batched butterfly: 39 independent reductions --------
#pragma unroll
    for (int m = 1; m < 64; m <<= 1) {
#pragma unroll
        for (int b = 0; b < 9; ++b) {
            mxA[b]  = fmaxf(mxA[b], __shfl_xor(mxA[b], m, 64));
            ZA[b]  += __shfl_xor(ZA[b], m, 64);
            SdA[b] += __shfl_xor(SdA[b], m, 64);
            tvA[b]  = fmaxf(tvA[b], __shfl_xor(tvA[b], m, 64));
        }
        z1 += __shfl_xor(z1, m, 64);
        zT += __shfl_xor(zT, m, 64);
        sc  = fmaxf(sc, __shfl_xor(sc, m, 64));
    }

    // ------------- ONE barrier: cross-wave combine --------------------------
    if (lane == 0) {
#pragma unroll
        for (int b = 0; b < 9; ++b)
            xch[h][b] = make_float4(mxA[b], ZA[b], SdA[b], tvA[b]);
        xch[h][9] = make_float4(z1, zT, sc, 0.0f);
    }
    __syncthreads();
#pragma unroll
    for (int b = 0; b < 9; ++b) {
        const float4 o = xch[h ^ 1][b];             // partner wave's values
        mxA[b]  = fmaxf(mxA[b], o.x);               // commutative combine:
        ZA[b]  += o.y;                              // both waves identical
        SdA[b] += o.z;
        tvA[b]  = fmaxf(tvA[b], o.w);
    }
    {
        const float4 o = xch[h ^ 1][9];
        z1 += o.x; zT += o.y; sc = fmaxf(sc, o.z);
    }

    // ------------- wave-uniform scalar tail ---------------------------------
    const float logZT = __logf(zT);
    const float ce    = __logf(z1) - sc;            // student cross-entropy

    float s1 = 0.0f, s2 = 0.0f, rowmax8 = SENT;
#pragma unroll
    for (int b = 0; b < 9; ++b) {
        const float mx = mxA[b], Z = ZA[b], Sd = SdA[b], tv = tvA[b];
        const float margin = fmaxf(tv - mx, 0.0f);  // exact: ties -> 0
        const float kd = TKD2 * (logZT - INV_TKD * __fdividef(Sd, Z));
        const float u  = tv * (kd - ce);
        const float w8 = __expf(margin * INV_TTHR); // margin in [0,~10]
        s1 += w8;
        s2  = fmaf(w8, u, s2);
        if (b < 8) rowmax8 = fmaxf(rowmax8, fmaxf(mx, tv));
    }

    if (tid == 0) {
        ws_ce[row] = ce;
        ws_g[row]  = s2 / s1;
        ws_m[row]  = rowmax8;
    }
}

// ---------------------------------------------------------------------------
// Kernel 2: single block. max_preds over rows, then f64-accumulated mean of
// CE_b + (ALPHA/max_preds) * G_b. Verified in rounds 3/7/9/10/13.
// ---------------------------------------------------------------------------
__global__ __launch_bounds__(256) void fin_kernel(
    const float* __restrict__ ce, const float* __restrict__ g,
    const float* __restrict__ m, float* __restrict__ out)
{
    __shared__ float  smax[4];
    __shared__ double ssum[4];
    const int tid  = threadIdx.x;
    const int lane = tid & 63;
    const int wid  = tid >> 6;

    float mx = SENT;
    for (int i = tid; i < B; i += 256) mx = fmaxf(mx, m[i]);
#pragma unroll
    for (int k = 1; k < 64; k <<= 1) mx = fmaxf(mx, __shfl_xor(mx, k, 64));
    if (lane == 0) smax[wid] = mx;
    __syncthreads();
    const float scale =
        ALPHA / fmaxf(fmaxf(smax[0], smax[1]), fmaxf(smax[2], smax[3]));

    double acc = 0.0;
    for (int i = tid; i < B; i += 256) acc += (double)(ce[i] + g[i] * scale);
#pragma unroll
    for (int k = 1; k < 64; k <<= 1) acc += __shfl_xor(acc, k, 64);
    if (lane == 0) ssum[wid] = acc;
    __syncthreads();
    if (tid == 0)
        out[0] = (float)((ssum[0] + ssum[1] + ssum[2] + ssum[3]) *
                         (1.0 / (double)B));
}

extern "C" void kernel_launch(void* const* d_in, const int* in_sizes, int n_in,
                              void* d_out, int out_size, void* d_ws, size_t ws_size,
                              hipStream_t stream)
{
    const float* T0 = (const float*)d_in[0];
    const float* T1 = (const float*)d_in[1];
    const float* T2 = (const float*)d_in[2];
    const float* T3 = (const float*)d_in[3];
    const float* T4 = (const float*)d_in[4];
    const float* T5 = (const float*)d_in[5];
    const float* T6 = (const float*)d_in[6];
    const float* T7 = (const float*)d_in[7];
    const float* S  = (const float*)d_in[8];
    const int*   TG = (const int*)d_in[9];

    float* ws = (float*)d_ws;
    float* ws_ce = ws;
    float* ws_g  = ws + B;
    float* ws_m  = ws + 2 * B;

    row_kernel<<<B, 128, 0, stream>>>(T0, T1, T2, T3, T4, T5, T6, T7,
                                      S, TG, ws_ce, ws_g, ws_m);
    fin_kernel<<<1, 256, 0, stream>>>(ws_ce, ws_g, ws_m, (float*)d_out);
}